// Round 1
// baseline (686.219 us; speedup 1.0000x reference)
//
#include <hip/hip_runtime.h>
#include <math.h>

// LMNN-style loss: outputs (2048,512,128) f32, label_inds (2048,511) i32 -> scalar.
// HBM-bound (512 MiB read once). One block per segment, wave-pair-per-point
// float4 coalesced reads, d2 staged in LDS, two cheap LDS passes, one atomic.

constexpr int NSEG = 2048;
constexpr int PPS  = 512;   // points per segment incl. center
constexpr int NPTS = 511;   // pts excluding center
constexpr int DIM  = 128;
constexpr int BLK  = 256;   // 4 waves; 2048 blocks -> 8 blocks/CU -> 32 waves/CU

__global__ __launch_bounds__(BLK) void lmnn_kernel(
    const float* __restrict__ outputs,
    const int*  __restrict__ labels,
    float* __restrict__ out)
{
    const int s    = blockIdx.x;
    const int tid  = threadIdx.x;
    const int lane = tid & 63;
    const int wave = tid >> 6;   // 0..3
    const int half = lane >> 5;  // which point of the pair this lane serves
    const int sl   = lane & 31;  // sub-lane within the 32-lane half

    __shared__ float d2s[NPTS];
    __shared__ unsigned char same_s[NPTS];
    __shared__ float red[8];

    const float*  seg  = outputs + (size_t)s * (PPS * DIM);
    const float4* seg4 = (const float4*)seg;
    const int*    lab  = labels + (size_t)s * NPTS;

    // same-label flags (lab[0] is scalar-broadcast)
    const int lab0 = lab[0];
    for (int j = tid; j < NPTS; j += BLK)
        same_s[j] = (lab[j] == lab0) ? 1 : 0;

    // this lane's center chunk: floats [4*sl .. 4*sl+3]
    const float4 c = seg4[sl];

    // d2 for all points; each wave covers 2 points per iter (float4/lane, 1KiB/instr)
    for (int jb = wave * 2; jb < NPTS; jb += 8) {
        const int j = jb + half;
        float v = 0.0f;
        if (j < NPTS) {
            float4 p = seg4[(size_t)(j + 1) * (DIM / 4) + sl];
            float dx = p.x - c.x;
            float dy = p.y - c.y;
            float dz = p.z - c.z;
            float dw = p.w - c.w;
            v = dx * dx + dy * dy + dz * dz + dw * dw;
        }
        // reduce across the 32-lane half (xor masks <32 stay within the half)
        #pragma unroll
        for (int o = 16; o > 0; o >>= 1)
            v += __shfl_xor(v, o, 64);
        if (sl == 0 && j < NPTS) d2s[j] = v;
    }
    __syncthreads();

    // pull = min d2 over same-label points (j=0 always same -> well-defined)
    float m = INFINITY;
    for (int j = tid; j < NPTS; j += BLK)
        if (same_s[j]) m = fminf(m, d2s[j]);
    #pragma unroll
    for (int o = 32; o > 0; o >>= 1)
        m = fminf(m, __shfl_xor(m, o, 64));
    if (lane == 0) red[wave] = m;
    __syncthreads();

    const float pull   = fminf(fminf(red[0], red[1]), fminf(red[2], red[3]));
    const float margin = 1.0f + pull;

    // push = sum over different-label points of max(margin - d2, 0)
    float p = 0.0f;
    for (int j = tid; j < NPTS; j += BLK)
        if (!same_s[j]) p += fmaxf(margin - d2s[j], 0.0f);
    #pragma unroll
    for (int o = 32; o > 0; o >>= 1)
        p += __shfl_xor(p, o, 64);
    if (lane == 0) red[4 + wave] = p;  // distinct slots from red[0..3]
    __syncthreads();

    if (tid == 0) {
        const float total = pull + red[4] + red[5] + red[6] + red[7];
        atomicAdd(out, total * (1.0f / (float)(NSEG * PPS)));
    }
}

extern "C" void kernel_launch(void* const* d_in, const int* in_sizes, int n_in,
                              void* d_out, int out_size, void* d_ws, size_t ws_size,
                              hipStream_t stream) {
    const float* outputs = (const float*)d_in[0];
    const int*   labels  = (const int*)d_in[1];
    float* out = (float*)d_out;

    // d_out is re-poisoned to 0xAA before every timed launch -> zero it on-stream.
    hipMemsetAsync(out, 0, sizeof(float) * out_size, stream);
    lmnn_kernel<<<NSEG, BLK, 0, stream>>>(outputs, labels, out);
}

// Round 3
// 651.188 us; speedup vs baseline: 1.0538x; 1.0538x over previous
//
#include <hip/hip_runtime.h>
#include <math.h>

// LMNN-style loss: outputs (2048,512,128) f32, label_inds (2048,511) i32 -> scalar.
// HBM-read-bound (512 MiB read once; floor ~85us @6.3TB/s). One block per segment.
// R3: same as R2 (4-deep load ILP, 8 points/wave-iter, nontemporal loads) but
// with native clang ext_vector_type float4 — __builtin_nontemporal_load rejects
// HIP_vector_type.

constexpr int NSEG = 2048;
constexpr int PPS  = 512;   // points per segment incl. center
constexpr int NPTS = 511;   // pts excluding center
constexpr int DIM  = 128;
constexpr int BLK  = 256;   // 4 waves; 2048 blocks -> 8 blocks/CU -> 32 waves/CU

typedef float f4_t __attribute__((ext_vector_type(4)));

__global__ __launch_bounds__(BLK) void lmnn_kernel(
    const float* __restrict__ outputs,
    const int*  __restrict__ labels,
    float* __restrict__ out)
{
    const int s    = blockIdx.x;
    const int tid  = threadIdx.x;
    const int lane = tid & 63;
    const int wave = tid >> 6;   // 0..3
    const int half = lane >> 5;  // which point of the pair this lane serves
    const int sl   = lane & 31;  // sub-lane within the 32-lane half

    __shared__ float d2s[NPTS];
    __shared__ unsigned char same_s[NPTS];
    __shared__ float red[8];

    const float* seg  = outputs + (size_t)s * (PPS * DIM);
    const f4_t*  seg4 = (const f4_t*)seg;
    const int*   lab  = labels + (size_t)s * NPTS;

    // same-label flags (lab[0] is scalar-broadcast)
    const int lab0 = lab[0];
    for (int j = tid; j < NPTS; j += BLK)
        same_s[j] = (lab[j] == lab0) ? 1 : 0;

    // this lane's center chunk: floats [4*sl .. 4*sl+3]
    const f4_t c = seg4[sl];

    // d2 for all points; each wave covers 8 points per iter:
    // 4 independent 1-KiB wave-loads in flight before any reduction.
    for (int jb = wave * 8; jb < NPTS; jb += 32) {
        f4_t p[4];
        int  jj[4];
        #pragma unroll
        for (int u = 0; u < 4; ++u) {
            const int j = jb + 2 * u + half;
            jj[u] = j;
            const f4_t* src = seg4 + (size_t)(j + 1) * (DIM / 4) + sl;
            // guard only trips at j==511 (last iter); clamp to a safe address
            const f4_t* safe = (j < NPTS) ? src : (seg4 + sl);
            p[u] = __builtin_nontemporal_load(safe);
        }
        #pragma unroll
        for (int u = 0; u < 4; ++u) {
            f4_t d = p[u] - c;
            float v = d.x * d.x + d.y * d.y + d.z * d.z + d.w * d.w;
            // reduce across the 32-lane half (xor masks <32 stay within the half)
            #pragma unroll
            for (int o = 16; o > 0; o >>= 1)
                v += __shfl_xor(v, o, 64);
            if (sl == 0 && jj[u] < NPTS) d2s[jj[u]] = v;
        }
    }
    __syncthreads();

    // pull = min d2 over same-label points (j=0 always same -> well-defined)
    float m = INFINITY;
    for (int j = tid; j < NPTS; j += BLK)
        if (same_s[j]) m = fminf(m, d2s[j]);
    #pragma unroll
    for (int o = 32; o > 0; o >>= 1)
        m = fminf(m, __shfl_xor(m, o, 64));
    if (lane == 0) red[wave] = m;
    __syncthreads();

    const float pull   = fminf(fminf(red[0], red[1]), fminf(red[2], red[3]));
    const float margin = 1.0f + pull;

    // push = sum over different-label points of max(margin - d2, 0)
    float p = 0.0f;
    for (int j = tid; j < NPTS; j += BLK)
        if (!same_s[j]) p += fmaxf(margin - d2s[j], 0.0f);
    #pragma unroll
    for (int o = 32; o > 0; o >>= 1)
        p += __shfl_xor(p, o, 64);
    if (lane == 0) red[4 + wave] = p;  // distinct slots from red[0..3]
    __syncthreads();

    if (tid == 0) {
        const float total = pull + red[4] + red[5] + red[6] + red[7];
        atomicAdd(out, total * (1.0f / (float)(NSEG * PPS)));
    }
}

extern "C" void kernel_launch(void* const* d_in, const int* in_sizes, int n_in,
                              void* d_out, int out_size, void* d_ws, size_t ws_size,
                              hipStream_t stream) {
    const float* outputs = (const float*)d_in[0];
    const int*   labels  = (const int*)d_in[1];
    float* out = (float*)d_out;

    // d_out is re-poisoned to 0xAA before every timed launch -> zero it on-stream.
    (void)hipMemsetAsync(out, 0, sizeof(float) * out_size, stream);
    lmnn_kernel<<<NSEG, BLK, 0, stream>>>(outputs, labels, out);
}